// Round 1
// baseline (1373.485 us; speedup 1.0000x reference)
//
#include <hip/hip_runtime.h>

#define N_NODES 50000
#define N_EDGES 1250000
#define HID 64
#define N_LAYERS 3
#define N_GRAPHS 64
#define EPS 1e-5f

// ---------------- embed gather: h[i][:] = emb[x[i]][:] (vectorized float4) ---
__global__ __launch_bounds__(256) void k_embed(const int* __restrict__ x,
                                               const float4* __restrict__ emb4,
                                               float4* __restrict__ h4) {
    int i = blockIdx.x * 256 + threadIdx.x;           // over N_NODES * 16
    if (i < N_NODES * 16) {
        int row = i >> 4, q = i & 15;
        h4[i] = emb4[x[row] * 16 + q];
    }
}

// ---------------- m = h @ W  (W: [64][64] row-major), 4 rows per block ------
__global__ __launch_bounds__(256) void k_linear(const float* __restrict__ h,
                                                const float* __restrict__ W,
                                                float* __restrict__ m) {
    __shared__ float Wl[HID * HID];   // 16 KB
    __shared__ float hl[4 * HID];
    int tid = threadIdx.x;
    for (int k = tid; k < HID * HID; k += 256) Wl[k] = W[k];
    int row0 = blockIdx.x * 4;        // 50000 % 4 == 0 -> exact
    for (int k = tid; k < 4 * HID; k += 256) hl[k] = h[row0 * HID + k];
    __syncthreads();
    int r = tid >> 6, c = tid & 63;
    float acc = 0.f;
#pragma unroll
    for (int k = 0; k < HID; ++k) acc += hl[r * HID + k] * Wl[k * HID + c];
    m[(row0 + r) * HID + c] = acc;
}

// ---------------- scatter-add: hn[dst] += m[src] * w  (64 lanes per edge) ---
__global__ __launch_bounds__(256) void k_scatter(const float* __restrict__ m,
                                                 const int* __restrict__ src,
                                                 const int* __restrict__ dst,
                                                 const float* __restrict__ w,
                                                 float* __restrict__ hn) {
    long long t = (long long)blockIdx.x * 256 + threadIdx.x;
    int e = (int)(t >> 6);
    int j = (int)(t & 63);
    if (e < N_EDGES) {
        int s = src[e], d = dst[e];
        float wt = w[e];
        atomicAdd(&hn[d * HID + j], m[s * HID + j] * wt);
    }
}

// ---------------- bias + LayerNorm + ReLU, one wave per row -----------------
__global__ __launch_bounds__(256) void k_ln(const float* __restrict__ hn,
                                            const float* __restrict__ bias,
                                            const float* __restrict__ g,
                                            const float* __restrict__ b,
                                            float* __restrict__ hout) {
    int t = blockIdx.x * 256 + threadIdx.x;
    int row = t >> 6, j = t & 63;
    if (row >= N_NODES) return;
    float v = hn[row * HID + j] + bias[j];
    float s = v;
#pragma unroll
    for (int off = 32; off; off >>= 1) s += __shfl_xor(s, off, 64);
    float mu = s * (1.f / 64.f);
    float d = v - mu;
    float vv = d * d;
#pragma unroll
    for (int off = 32; off; off >>= 1) vv += __shfl_xor(vv, off, 64);
    float var = vv * (1.f / 64.f);
    float y = d * rsqrtf(var + EPS) * g[j] + b[j];
    hout[row * HID + j] = fmaxf(y, 0.f);
}

// ---------------- pooling: per-graph sum / max / count ----------------------
__global__ __launch_bounds__(256) void k_pool(const float* __restrict__ h,
                                              const int* __restrict__ batch,
                                              float* __restrict__ sums,
                                              unsigned* __restrict__ maxs,
                                              int* __restrict__ counts) {
    int t = blockIdx.x * 256 + threadIdx.x;
    int row = t >> 6, j = t & 63;
    if (row >= N_NODES) return;
    int gph = batch[row];
    float v = h[row * HID + j];
    atomicAdd(&sums[gph * HID + j], v);
    atomicMax(&maxs[gph * HID + j], __float_as_uint(v));  // v >= 0 post-ReLU
    if (j == 0) atomicAdd(&counts[gph], 1);
}

// ---------------- final MLP: relu([mean,max] @ W1 + b1) @ W2 + b2 -----------
__global__ __launch_bounds__(64) void k_mlp(const float* __restrict__ sums,
                                            const unsigned* __restrict__ maxs,
                                            const int* __restrict__ counts,
                                            const float* __restrict__ W1,
                                            const float* __restrict__ b1,
                                            const float* __restrict__ W2,
                                            const float* __restrict__ b2,
                                            float* __restrict__ out) {
    int gph = blockIdx.x;
    int j = threadIdx.x;          // 64 threads
    __shared__ float gv[2 * HID];
    int cnt = counts[gph];
    float inv = 1.f / fmaxf((float)cnt, 1.f);
    gv[j] = sums[gph * HID + j] * inv;
    float mx = __uint_as_float(maxs[gph * HID + j]);
    gv[HID + j] = (cnt > 0) ? mx : 0.f;
    __syncthreads();
    float acc = b1[j];
#pragma unroll
    for (int k = 0; k < 2 * HID; ++k) acc += gv[k] * W1[k * HID + j];
    acc = fmaxf(acc, 0.f);
    float p = acc * W2[j];
#pragma unroll
    for (int off = 32; off; off >>= 1) p += __shfl_xor(p, off, 64);
    if (j == 0) out[gph] = p + b2[0];
}

extern "C" void kernel_launch(void* const* d_in, const int* in_sizes, int n_in,
                              void* d_out, int out_size, void* d_ws, size_t ws_size,
                              hipStream_t stream) {
    const int*   x     = (const int*)d_in[0];
    const int*   ei    = (const int*)d_in[1];
    const float* ew    = (const float*)d_in[2];
    const int*   batch = (const int*)d_in[3];
    const float* emb   = (const float*)d_in[4];
    const float* convW = (const float*)d_in[5];
    const float* convB = (const float*)d_in[6];
    const float* lnG   = (const float*)d_in[7];
    const float* lnB   = (const float*)d_in[8];
    const float* W1    = (const float*)d_in[9];
    const float* b1    = (const float*)d_in[10];
    const float* W2    = (const float*)d_in[11];
    const float* b2    = (const float*)d_in[12];
    float* out = (float*)d_out;

    float* hA   = (float*)d_ws;                 // [N_NODES][HID]
    float* hB   = hA + (size_t)N_NODES * HID;   // [N_NODES][HID] (scatter target)
    float* m    = hB + (size_t)N_NODES * HID;   // [N_NODES][HID]
    float* sums = m + (size_t)N_NODES * HID;    // [N_GRAPHS][HID]
    unsigned* maxs = (unsigned*)(sums + N_GRAPHS * HID);
    int*      counts = (int*)(maxs + N_GRAPHS * HID);

    const int* src = ei;
    const int* dst = ei + N_EDGES;

    // zero pooling scratch (sums, maxs, counts) — ws is poisoned each call
    hipMemsetAsync(sums, 0, (2 * N_GRAPHS * HID + N_GRAPHS) * sizeof(float), stream);

    k_embed<<<(N_NODES * 16 + 255) / 256, 256, 0, stream>>>(
        x, (const float4*)emb, (float4*)hA);

    for (int L = 0; L < N_LAYERS; ++L) {
        k_linear<<<N_NODES / 4, 256, 0, stream>>>(hA, convW + L * HID * HID, m);
        hipMemsetAsync(hB, 0, (size_t)N_NODES * HID * sizeof(float), stream);
        k_scatter<<<(int)(((long long)N_EDGES * 64) / 256), 256, 0, stream>>>(
            m, src, dst, ew, hB);
        k_ln<<<(N_NODES * 64) / 256, 256, 0, stream>>>(
            hB, convB + L * HID, lnG + L * HID, lnB + L * HID, hA);
    }

    k_pool<<<(N_NODES * 64) / 256, 256, 0, stream>>>(hA, batch, sums, maxs, counts);
    k_mlp<<<N_GRAPHS, 64, 0, stream>>>(sums, maxs, counts, W1, b1, W2, b2, out);
}

// Round 3
// 777.470 us; speedup vs baseline: 1.7666x; 1.7666x over previous
//
#include <hip/hip_runtime.h>

#define N_NODES 50000
#define N_EDGES 1250000
#define HID 64
#define N_LAYERS 3
#define N_GRAPHS 64
#define EPS 1e-5f

// ---------------- embed gather: h[i][:] = emb[x[i]][:] (vectorized float4) ---
__global__ __launch_bounds__(256) void k_embed(const int* __restrict__ x,
                                               const float4* __restrict__ emb4,
                                               float4* __restrict__ h4) {
    int i = blockIdx.x * 256 + threadIdx.x;           // over N_NODES * 16
    if (i < N_NODES * 16) {
        int row = i >> 4, q = i & 15;
        h4[i] = emb4[x[row] * 16 + q];
    }
}

// ---------------- m = h @ W  (W: [64][64] row-major), 4 rows per block ------
__global__ __launch_bounds__(256) void k_linear(const float* __restrict__ h,
                                                const float* __restrict__ W,
                                                float* __restrict__ m) {
    __shared__ float Wl[HID * HID];   // 16 KB
    __shared__ float hl[4 * HID];
    int tid = threadIdx.x;
    for (int k = tid; k < HID * HID; k += 256) Wl[k] = W[k];
    int row0 = blockIdx.x * 4;        // 50000 % 4 == 0 -> exact
    for (int k = tid; k < 4 * HID; k += 256) hl[k] = h[row0 * HID + k];
    __syncthreads();
    int r = tid >> 6, c = tid & 63;
    float acc = 0.f;
#pragma unroll
    for (int k = 0; k < HID; ++k) acc += hl[r * HID + k] * Wl[k * HID + c];
    m[(row0 + r) * HID + c] = acc;
}

// ---------------- CSR build: histogram of dst ------------------------------
__global__ __launch_bounds__(256) void k_hist(const int* __restrict__ dst,
                                              int* __restrict__ deg) {
    int e = blockIdx.x * 256 + threadIdx.x;
    if (e < N_EDGES) atomicAdd(&deg[dst[e]], 1);
}

// ---------------- single-block exclusive scan over 50000 degrees ------------
__global__ __launch_bounds__(1024) void k_scan(const int* __restrict__ deg,
                                               int* __restrict__ rowptr) {
    __shared__ int part[1024];
    const int CH = (N_NODES + 1023) / 1024;   // 49
    int t = threadIdx.x;
    int beg = t * CH, end = min(beg + CH, N_NODES);
    int s = 0;
    for (int i = beg; i < end; ++i) s += deg[i];
    part[t] = s;
    __syncthreads();
    for (int off = 1; off < 1024; off <<= 1) {
        int v = (t >= off) ? part[t - off] : 0;
        __syncthreads();
        part[t] += v;
        __syncthreads();
    }
    int run = (t > 0) ? part[t - 1] : 0;      // exclusive prefix of my chunk
    for (int i = beg; i < end; ++i) { rowptr[i] = run; run += deg[i]; }
    if (t == 1023) rowptr[N_NODES] = run;     // == N_EDGES
}

// ---------------- CSR fill: packed (src, weight_bits) per slot --------------
__global__ __launch_bounds__(256) void k_fill(const int* __restrict__ src,
                                              const int* __restrict__ dst,
                                              const float* __restrict__ w,
                                              int* __restrict__ cursor,
                                              int2* __restrict__ csr) {
    int e = blockIdx.x * 256 + threadIdx.x;
    if (e < N_EDGES) {
        int d = dst[e];
        int pos = atomicAdd(&cursor[d], 1);
        csr[pos] = make_int2(src[e], __float_as_int(w[e]));
    }
}

// ------- fused: atomic-free gather-aggregate + bias + LayerNorm + ReLU ------
// one wave per node; lane = channel
__global__ __launch_bounds__(256) void k_agg_ln(const float* __restrict__ m,
                                                const int* __restrict__ rowptr,
                                                const int2* __restrict__ csr,
                                                const float* __restrict__ bias,
                                                const float* __restrict__ g,
                                                const float* __restrict__ b,
                                                float* __restrict__ hout) {
    int t = blockIdx.x * 256 + threadIdx.x;
    int row = t >> 6, j = t & 63;
    if (row >= N_NODES) return;
    int p0 = rowptr[row], p1 = rowptr[row + 1];
    float acc = 0.f;
    for (int p = p0; p < p1; ++p) {
        int2 sw = csr[p];                       // wave-uniform 8B load
        acc += m[sw.x * HID + j] * __int_as_float(sw.y);
    }
    float v = acc + bias[j];
    float s = v;
#pragma unroll
    for (int off = 32; off; off >>= 1) s += __shfl_xor(s, off, 64);
    float mu = s * (1.f / 64.f);
    float d = v - mu;
    float vv = d * d;
#pragma unroll
    for (int off = 32; off; off >>= 1) vv += __shfl_xor(vv, off, 64);
    float var = vv * (1.f / 64.f);
    float y = d * rsqrtf(var + EPS) * g[j] + b[j];
    hout[row * HID + j] = fmaxf(y, 0.f);
}

// ---------------- graph boundaries: start[g] = lower_bound(batch, g) --------
__global__ __launch_bounds__(128) void k_bounds(const int* __restrict__ batch,
                                                int* __restrict__ start) {
    int t = threadIdx.x;
    if (t > N_GRAPHS) return;
    int lo = 0, hi = N_NODES;
    while (lo < hi) {
        int mid = (lo + hi) >> 1;
        if (batch[mid] < t) lo = mid + 1; else hi = mid;
    }
    start[t] = lo;
}

// ---------------- pooling: sliced segmented reduction -----------------------
#define NSLICE 16
__global__ __launch_bounds__(256) void k_pool2(const float* __restrict__ h,
                                               const int* __restrict__ start,
                                               float* __restrict__ sums,
                                               unsigned* __restrict__ maxs) {
    int gph = blockIdx.x >> 4;          // / NSLICE
    int sl  = blockIdx.x & (NSLICE - 1);
    int s = start[gph], e1 = start[gph + 1];
    int len = e1 - s;
    int chunk = (len + NSLICE - 1) / NSLICE;
    int r0 = s + sl * chunk;
    int r1 = min(r0 + chunk, e1);
    int j = threadIdx.x & 63, wv = threadIdx.x >> 6;
    float sm = 0.f, mx = 0.f;           // post-ReLU values >= 0
    for (int r = r0 + wv; r < r1; r += 4) {
        float v = h[r * HID + j];
        sm += v;
        mx = fmaxf(mx, v);
    }
    atomicAdd(&sums[gph * HID + j], sm);
    atomicMax(&maxs[gph * HID + j], __float_as_uint(mx));
}

// ---------------- final MLP: relu([mean,max] @ W1 + b1) @ W2 + b2 -----------
__global__ __launch_bounds__(64) void k_mlp(const float* __restrict__ sums,
                                            const unsigned* __restrict__ maxs,
                                            const int* __restrict__ start,
                                            const float* __restrict__ W1,
                                            const float* __restrict__ b1,
                                            const float* __restrict__ W2,
                                            const float* __restrict__ b2,
                                            float* __restrict__ out) {
    int gph = blockIdx.x;
    int j = threadIdx.x;          // 64 threads
    __shared__ float gv[2 * HID];
    int cnt = start[gph + 1] - start[gph];
    float inv = 1.f / fmaxf((float)cnt, 1.f);
    gv[j] = sums[gph * HID + j] * inv;
    float mx = __uint_as_float(maxs[gph * HID + j]);
    gv[HID + j] = (cnt > 0) ? mx : 0.f;
    __syncthreads();
    float acc = b1[j];
#pragma unroll
    for (int k = 0; k < 2 * HID; ++k) acc += gv[k] * W1[k * HID + j];
    acc = fmaxf(acc, 0.f);
    float p = acc * W2[j];
#pragma unroll
    for (int off = 32; off; off >>= 1) p += __shfl_xor(p, off, 64);
    if (j == 0) out[gph] = p + b2[0];
}

extern "C" void kernel_launch(void* const* d_in, const int* in_sizes, int n_in,
                              void* d_out, int out_size, void* d_ws, size_t ws_size,
                              hipStream_t stream) {
    const int*   x     = (const int*)d_in[0];
    const int*   ei    = (const int*)d_in[1];
    const float* ew    = (const float*)d_in[2];
    const int*   batch = (const int*)d_in[3];
    const float* emb   = (const float*)d_in[4];
    const float* convW = (const float*)d_in[5];
    const float* convB = (const float*)d_in[6];
    const float* lnG   = (const float*)d_in[7];
    const float* lnB   = (const float*)d_in[8];
    const float* W1    = (const float*)d_in[9];
    const float* b1    = (const float*)d_in[10];
    const float* W2    = (const float*)d_in[11];
    const float* b2    = (const float*)d_in[12];
    float* out = (float*)d_out;

    // ---- workspace layout ----
    float* hA     = (float*)d_ws;                       // 12.8 MB
    float* m      = hA + (size_t)N_NODES * HID;         // 12.8 MB
    int*   rowptr = (int*)(m + (size_t)N_NODES * HID);  // 50001
    int*   deg    = rowptr + (N_NODES + 1);             // 50000 (also cursor)
    int2*  csr    = (int2*)(deg + N_NODES);             // 1.25M * 8B = 10 MB
    float* sums   = (float*)(csr + N_EDGES);            // 64*64
    unsigned* maxs = (unsigned*)(sums + N_GRAPHS * HID);
    int*   start  = (int*)(maxs + N_GRAPHS * HID);      // 65

    const int* src = ei;
    const int* dst = ei + N_EDGES;

    // ---- CSR build (per call; ws is re-poisoned) ----
    hipMemsetAsync(deg, 0, N_NODES * sizeof(int), stream);
    k_hist<<<(N_EDGES + 255) / 256, 256, 0, stream>>>(dst, deg);
    k_scan<<<1, 1024, 0, stream>>>(deg, rowptr);
    // cursor := rowptr[0..N_NODES-1]
    hipMemcpyAsync(deg, rowptr, N_NODES * sizeof(int),
                   hipMemcpyDeviceToDevice, stream);
    k_fill<<<(N_EDGES + 255) / 256, 256, 0, stream>>>(src, dst, ew, deg, csr);

    k_bounds<<<1, 128, 0, stream>>>(batch, start);
    hipMemsetAsync(sums, 0, 2 * N_GRAPHS * HID * sizeof(float), stream);

    k_embed<<<(N_NODES * 16 + 255) / 256, 256, 0, stream>>>(
        x, (const float4*)emb, (float4*)hA);

    for (int L = 0; L < N_LAYERS; ++L) {
        k_linear<<<N_NODES / 4, 256, 0, stream>>>(hA, convW + L * HID * HID, m);
        k_agg_ln<<<(N_NODES + 3) / 4, 256, 0, stream>>>(
            m, rowptr, csr, convB + L * HID, lnG + L * HID, lnB + L * HID, hA);
    }

    k_pool2<<<N_GRAPHS * NSLICE, 256, 0, stream>>>(hA, start, sums, maxs);
    k_mlp<<<N_GRAPHS, 64, 0, stream>>>(sums, maxs, start, W1, b1, W2, b2, out);
}

// Round 4
// 637.403 us; speedup vs baseline: 2.1548x; 1.2197x over previous
//
#include <hip/hip_runtime.h>

#define N_NODES 50000
#define N_EDGES 1250000
#define HID 64
#define N_LAYERS 3
#define N_GRAPHS 64
#define EPS 1e-5f

// ---------------- embed gather: h[i][:] = emb[x[i]][:] (vectorized float4) ---
__global__ __launch_bounds__(256) void k_embed(const int* __restrict__ x,
                                               const float4* __restrict__ emb4,
                                               float4* __restrict__ h4) {
    int i = blockIdx.x * 256 + threadIdx.x;           // over N_NODES * 16
    if (i < N_NODES * 16) {
        int row = i >> 4, q = i & 15;
        h4[i] = emb4[x[row] * 16 + q];
    }
}

// ---------------- m = h @ W  (W: [64][64] row-major), 4 rows per block ------
__global__ __launch_bounds__(256) void k_linear(const float* __restrict__ h,
                                                const float* __restrict__ W,
                                                float* __restrict__ m) {
    __shared__ float Wl[HID * HID];   // 16 KB
    __shared__ float hl[4 * HID];
    int tid = threadIdx.x;
    for (int k = tid; k < HID * HID; k += 256) Wl[k] = W[k];
    int row0 = blockIdx.x * 4;        // 50000 % 4 == 0 -> exact
    for (int k = tid; k < 4 * HID; k += 256) hl[k] = h[row0 * HID + k];
    __syncthreads();
    int r = tid >> 6, c = tid & 63;
    float acc = 0.f;
#pragma unroll
    for (int k = 0; k < HID; ++k) acc += hl[r * HID + k] * Wl[k * HID + c];
    m[(row0 + r) * HID + c] = acc;
}

// ---------------- CSR build: histogram of dst ------------------------------
__global__ __launch_bounds__(256) void k_hist(const int* __restrict__ dst,
                                              int* __restrict__ deg) {
    int e = blockIdx.x * 256 + threadIdx.x;
    if (e < N_EDGES) atomicAdd(&deg[dst[e]], 1);
}

// ------- single-block exclusive scan; ALSO rewrites deg -> cursor copy ------
__global__ __launch_bounds__(1024) void k_scan(int* __restrict__ deg,
                                               int* __restrict__ rowptr) {
    __shared__ int part[1024];
    const int CH = (N_NODES + 1023) / 1024;   // 49
    int t = threadIdx.x;
    int beg = t * CH, end = min(beg + CH, N_NODES);
    int s = 0;
    for (int i = beg; i < end; ++i) s += deg[i];
    part[t] = s;
    __syncthreads();
    for (int off = 1; off < 1024; off <<= 1) {
        int v = (t >= off) ? part[t - off] : 0;
        __syncthreads();
        part[t] += v;
        __syncthreads();
    }
    int run = (t > 0) ? part[t - 1] : 0;      // exclusive prefix of my chunk
    for (int i = beg; i < end; ++i) {
        int d = deg[i];
        rowptr[i] = run;
        deg[i] = run;                          // deg becomes the fill cursor
        run += d;
    }
    if (t == 1023) rowptr[N_NODES] = run;     // == N_EDGES
}

// ---------------- CSR fill: packed (src, weight_bits) per slot --------------
__global__ __launch_bounds__(256) void k_fill(const int* __restrict__ src,
                                              const int* __restrict__ dst,
                                              const float* __restrict__ w,
                                              int* __restrict__ cursor,
                                              int2* __restrict__ csr) {
    int e = blockIdx.x * 256 + threadIdx.x;
    if (e < N_EDGES) {
        int d = dst[e];
        int pos = atomicAdd(&cursor[d], 1);
        csr[pos] = make_int2(src[e], __float_as_int(w[e]));
    }
}

// ------- fused: atomic-free gather-aggregate + bias + LayerNorm + ReLU ------
// one wave per node; lane = channel; 8-deep software-pipelined edge loop
__global__ __launch_bounds__(256) void k_agg_ln(const float* __restrict__ m,
                                                const int* __restrict__ rowptr,
                                                const int2* __restrict__ csr,
                                                const float* __restrict__ bias,
                                                const float* __restrict__ g,
                                                const float* __restrict__ b,
                                                float* __restrict__ hout) {
    int t = blockIdx.x * 256 + threadIdx.x;
    int row = t >> 6, j = t & 63;
    if (row >= N_NODES) return;
    int p0 = rowptr[row], p1 = rowptr[row + 1];
    float a0 = 0.f, a1 = 0.f, a2 = 0.f, a3 = 0.f;
    float a4 = 0.f, a5 = 0.f, a6 = 0.f, a7 = 0.f;
    for (int p = p0; p < p1; p += 8) {
        int2 e0, e1, e2, e3, e4, e5, e6, e7;
        int last = p1 - 1;
        // 8 independent (clamped) csr loads — issued together
        e0 = csr[min(p + 0, last)];
        e1 = csr[min(p + 1, last)];
        e2 = csr[min(p + 2, last)];
        e3 = csr[min(p + 3, last)];
        e4 = csr[min(p + 4, last)];
        e5 = csr[min(p + 5, last)];
        e6 = csr[min(p + 6, last)];
        e7 = csr[min(p + 7, last)];
        // 8 independent m-row gathers in flight; tail killed by w=0
        float w0 = (p + 0 < p1) ? __int_as_float(e0.y) : 0.f;
        float w1 = (p + 1 < p1) ? __int_as_float(e1.y) : 0.f;
        float w2 = (p + 2 < p1) ? __int_as_float(e2.y) : 0.f;
        float w3 = (p + 3 < p1) ? __int_as_float(e3.y) : 0.f;
        float w4 = (p + 4 < p1) ? __int_as_float(e4.y) : 0.f;
        float w5 = (p + 5 < p1) ? __int_as_float(e5.y) : 0.f;
        float w6 = (p + 6 < p1) ? __int_as_float(e6.y) : 0.f;
        float w7 = (p + 7 < p1) ? __int_as_float(e7.y) : 0.f;
        a0 += m[e0.x * HID + j] * w0;
        a1 += m[e1.x * HID + j] * w1;
        a2 += m[e2.x * HID + j] * w2;
        a3 += m[e3.x * HID + j] * w3;
        a4 += m[e4.x * HID + j] * w4;
        a5 += m[e5.x * HID + j] * w5;
        a6 += m[e6.x * HID + j] * w6;
        a7 += m[e7.x * HID + j] * w7;
    }
    float acc = ((a0 + a1) + (a2 + a3)) + ((a4 + a5) + (a6 + a7));
    float v = acc + bias[j];
    float s = v;
#pragma unroll
    for (int off = 32; off; off >>= 1) s += __shfl_xor(s, off, 64);
    float mu = s * (1.f / 64.f);
    float d = v - mu;
    float vv = d * d;
#pragma unroll
    for (int off = 32; off; off >>= 1) vv += __shfl_xor(vv, off, 64);
    float var = vv * (1.f / 64.f);
    float y = d * rsqrtf(var + EPS) * g[j] + b[j];
    hout[row * HID + j] = fmaxf(y, 0.f);
}

// ---------------- graph boundaries: start[g] = lower_bound(batch, g) --------
__global__ __launch_bounds__(128) void k_bounds(const int* __restrict__ batch,
                                                int* __restrict__ start) {
    int t = threadIdx.x;
    if (t > N_GRAPHS) return;
    int lo = 0, hi = N_NODES;
    while (lo < hi) {
        int mid = (lo + hi) >> 1;
        if (batch[mid] < t) lo = mid + 1; else hi = mid;
    }
    start[t] = lo;
}

// ---------------- pooling: sliced segmented reduction -----------------------
#define NSLICE 16
__global__ __launch_bounds__(256) void k_pool2(const float* __restrict__ h,
                                               const int* __restrict__ start,
                                               float* __restrict__ sums,
                                               unsigned* __restrict__ maxs) {
    int gph = blockIdx.x >> 4;          // / NSLICE
    int sl  = blockIdx.x & (NSLICE - 1);
    int s = start[gph], e1 = start[gph + 1];
    int len = e1 - s;
    int chunk = (len + NSLICE - 1) / NSLICE;
    int r0 = s + sl * chunk;
    int r1 = min(r0 + chunk, e1);
    int j = threadIdx.x & 63, wv = threadIdx.x >> 6;
    float sm = 0.f, mx = 0.f;           // post-ReLU values >= 0
    for (int r = r0 + wv; r < r1; r += 4) {
        float v = h[r * HID + j];
        sm += v;
        mx = fmaxf(mx, v);
    }
    atomicAdd(&sums[gph * HID + j], sm);
    atomicMax(&maxs[gph * HID + j], __float_as_uint(mx));
}

// ---------------- final MLP: relu([mean,max] @ W1 + b1) @ W2 + b2 -----------
__global__ __launch_bounds__(64) void k_mlp(const float* __restrict__ sums,
                                            const unsigned* __restrict__ maxs,
                                            const int* __restrict__ start,
                                            const float* __restrict__ W1,
                                            const float* __restrict__ b1,
                                            const float* __restrict__ W2,
                                            const float* __restrict__ b2,
                                            float* __restrict__ out) {
    int gph = blockIdx.x;
    int j = threadIdx.x;          // 64 threads
    __shared__ float gv[2 * HID];
    int cnt = start[gph + 1] - start[gph];
    float inv = 1.f / fmaxf((float)cnt, 1.f);
    gv[j] = sums[gph * HID + j] * inv;
    float mx = __uint_as_float(maxs[gph * HID + j]);
    gv[HID + j] = (cnt > 0) ? mx : 0.f;
    __syncthreads();
    float acc = b1[j];
#pragma unroll
    for (int k = 0; k < 2 * HID; ++k) acc += gv[k] * W1[k * HID + j];
    acc = fmaxf(acc, 0.f);
    float p = acc * W2[j];
#pragma unroll
    for (int off = 32; off; off >>= 1) p += __shfl_xor(p, off, 64);
    if (j == 0) out[gph] = p + b2[0];
}

extern "C" void kernel_launch(void* const* d_in, const int* in_sizes, int n_in,
                              void* d_out, int out_size, void* d_ws, size_t ws_size,
                              hipStream_t stream) {
    const int*   x     = (const int*)d_in[0];
    const int*   ei    = (const int*)d_in[1];
    const float* ew    = (const float*)d_in[2];
    const int*   batch = (const int*)d_in[3];
    const float* emb   = (const float*)d_in[4];
    const float* convW = (const float*)d_in[5];
    const float* convB = (const float*)d_in[6];
    const float* lnG   = (const float*)d_in[7];
    const float* lnB   = (const float*)d_in[8];
    const float* W1    = (const float*)d_in[9];
    const float* b1    = (const float*)d_in[10];
    const float* W2    = (const float*)d_in[11];
    const float* b2    = (const float*)d_in[12];
    float* out = (float*)d_out;

    // ---- workspace layout ----
    float* hA     = (float*)d_ws;                       // 12.8 MB
    float* m      = hA + (size_t)N_NODES * HID;         // 12.8 MB
    int*   rowptr = (int*)(m + (size_t)N_NODES * HID);  // 50001
    int*   deg    = rowptr + (N_NODES + 1);             // 50000 (becomes cursor)
    int2*  csr    = (int2*)(deg + N_NODES);             // 1.25M * 8B = 10 MB
    float* sums   = (float*)(csr + N_EDGES);            // 64*64
    unsigned* maxs = (unsigned*)(sums + N_GRAPHS * HID);
    int*   start  = (int*)(maxs + N_GRAPHS * HID);      // 65

    const int* src = ei;
    const int* dst = ei + N_EDGES;

    // ---- CSR build (per call; ws is re-poisoned) ----
    hipMemsetAsync(deg, 0, N_NODES * sizeof(int), stream);
    k_hist<<<(N_EDGES + 255) / 256, 256, 0, stream>>>(dst, deg);
    k_scan<<<1, 1024, 0, stream>>>(deg, rowptr);   // also turns deg into cursor
    k_fill<<<(N_EDGES + 255) / 256, 256, 0, stream>>>(src, dst, ew, deg, csr);

    k_bounds<<<1, 128, 0, stream>>>(batch, start);
    hipMemsetAsync(sums, 0, 2 * N_GRAPHS * HID * sizeof(float), stream);

    k_embed<<<(N_NODES * 16 + 255) / 256, 256, 0, stream>>>(
        x, (const float4*)emb, (float4*)hA);

    for (int L = 0; L < N_LAYERS; ++L) {
        k_linear<<<N_NODES / 4, 256, 0, stream>>>(hA, convW + L * HID * HID, m);
        k_agg_ln<<<(N_NODES + 3) / 4, 256, 0, stream>>>(
            m, rowptr, csr, convB + L * HID, lnG + L * HID, lnB + L * HID, hA);
    }

    k_pool2<<<N_GRAPHS * NSLICE, 256, 0, stream>>>(hA, start, sums, maxs);
    k_mlp<<<N_GRAPHS, 64, 0, stream>>>(sums, maxs, start, W1, b1, W2, b2, out);
}

// Round 6
// 522.911 us; speedup vs baseline: 2.6266x; 1.2190x over previous
//
#include <hip/hip_runtime.h>

#define N_NODES 50000
#define N_EDGES 1250000
#define HID 64
#define N_LAYERS 3
#define N_GRAPHS 64
#define EPS 1e-5f

#define SCAN_B 256
#define SCAN_NB ((N_NODES + SCAN_B - 1) / SCAN_B)   // 196

// ------ m = h @ W ; optional row gather via xidx (fuses embedding layer) ----
__global__ __launch_bounds__(256) void k_linear(const float* __restrict__ h,
                                                const int* __restrict__ xidx,
                                                const float* __restrict__ W,
                                                float* __restrict__ m) {
    __shared__ float Wl[HID * HID];   // 16 KB
    __shared__ float hl[4 * HID];
    int tid = threadIdx.x;
    for (int k = tid; k < HID * HID; k += 256) Wl[k] = W[k];
    int row0 = blockIdx.x * 4;        // 50000 % 4 == 0 -> exact
    {
        int rr = row0 + (tid >> 6);
        int srcrow = xidx ? xidx[rr] : rr;
        hl[tid] = h[srcrow * HID + (tid & 63)];
    }
    __syncthreads();
    int r = tid >> 6, c = tid & 63;
    float acc = 0.f;
#pragma unroll
    for (int k = 0; k < HID; ++k) acc += hl[r * HID + k] * Wl[k * HID + c];
    m[(row0 + r) * HID + c] = acc;
}

// ---------------- CSR build: histogram of dst ------------------------------
__global__ __launch_bounds__(256) void k_hist(const int* __restrict__ dst,
                                              int* __restrict__ deg) {
    int e = blockIdx.x * 256 + threadIdx.x;
    if (e < N_EDGES) atomicAdd(&deg[dst[e]], 1);
}

// ---------------- scan phase A: per-block sums ------------------------------
__global__ __launch_bounds__(SCAN_B) void k_scan_a(const int* __restrict__ deg,
                                                   int* __restrict__ bsum) {
    __shared__ int s[SCAN_B];
    int t = threadIdx.x;
    int i = blockIdx.x * SCAN_B + t;
    s[t] = (i < N_NODES) ? deg[i] : 0;
    __syncthreads();
    for (int off = SCAN_B / 2; off; off >>= 1) {
        if (t < off) s[t] += s[t + off];
        __syncthreads();
    }
    if (t == 0) bsum[blockIdx.x] = s[0];
}

// ------ scan phase B (1 block): scan bsum; also graph bounds + zero pools ---
__global__ __launch_bounds__(256) void k_scan_b(int* __restrict__ bsum,
                                                int* __restrict__ rowptr,
                                                const int* __restrict__ batch,
                                                int* __restrict__ start,
                                                float* __restrict__ sums,
                                                unsigned* __restrict__ maxs) {
    __shared__ int s[256];
    int t = threadIdx.x;
    int v = (t < SCAN_NB) ? bsum[t] : 0;
    s[t] = v;
    __syncthreads();
    for (int off = 1; off < 256; off <<= 1) {
        int u = (t >= off) ? s[t - off] : 0;
        __syncthreads();
        s[t] += u;
        __syncthreads();
    }
    if (t < SCAN_NB) bsum[t] = s[t] - v;       // exclusive block offset
    if (t == 255) rowptr[N_NODES] = s[255];    // == N_EDGES
    // graph boundaries: start[g] = lower_bound(batch, g)
    if (t <= N_GRAPHS) {
        int lo = 0, hi = N_NODES;
        while (lo < hi) {
            int mid = (lo + hi) >> 1;
            if (batch[mid] < t) lo = mid + 1; else hi = mid;
        }
        start[t] = lo;
    }
    // zero pooling scratch
    for (int k = t; k < N_GRAPHS * HID; k += 256) {
        sums[k] = 0.f;
        maxs[k] = 0u;
    }
}

// ------ scan phase C: local scan + offset; rowptr & cursor (deg in place) ---
__global__ __launch_bounds__(SCAN_B) void k_scan_c(int* __restrict__ deg,
                                                   const int* __restrict__ bsum,
                                                   int* __restrict__ rowptr) {
    __shared__ int s[SCAN_B];
    int t = threadIdx.x;
    int i = blockIdx.x * SCAN_B + t;
    int v = (i < N_NODES) ? deg[i] : 0;
    s[t] = v;
    __syncthreads();
    for (int off = 1; off < SCAN_B; off <<= 1) {
        int u = (t >= off) ? s[t - off] : 0;
        __syncthreads();
        s[t] += u;
        __syncthreads();
    }
    int excl = s[t] - v + bsum[blockIdx.x];
    if (i < N_NODES) {
        rowptr[i] = excl;
        deg[i] = excl;                         // becomes the fill cursor
    }
}

// ---------------- CSR fill: packed (src, weight_bits) per slot --------------
__global__ __launch_bounds__(256) void k_fill(const int* __restrict__ src,
                                              const int* __restrict__ dst,
                                              const float* __restrict__ w,
                                              int* __restrict__ cursor,
                                              int2* __restrict__ csr) {
    int e = blockIdx.x * 256 + threadIdx.x;
    if (e < N_EDGES) {
        int d = dst[e];
        int pos = atomicAdd(&cursor[d], 1);
        csr[pos] = make_int2(src[e], __float_as_int(w[e]));
    }
}

// ------- fused: atomic-free gather-aggregate + bias + LayerNorm + ReLU ------
// one wave per node; lane = channel; 8-deep software-pipelined edge loop
__global__ __launch_bounds__(256) void k_agg_ln(const float* __restrict__ m,
                                                const int* __restrict__ rowptr,
                                                const int2* __restrict__ csr,
                                                const float* __restrict__ bias,
                                                const float* __restrict__ g,
                                                const float* __restrict__ b,
                                                float* __restrict__ hout) {
    int t = blockIdx.x * 256 + threadIdx.x;
    int row = t >> 6, j = t & 63;
    if (row >= N_NODES) return;
    int p0 = rowptr[row], p1 = rowptr[row + 1];
    float a0 = 0.f, a1 = 0.f, a2 = 0.f, a3 = 0.f;
    float a4 = 0.f, a5 = 0.f, a6 = 0.f, a7 = 0.f;
    for (int p = p0; p < p1; p += 8) {
        int2 e0, e1, e2, e3, e4, e5, e6, e7;
        int last = p1 - 1;
        e0 = csr[min(p + 0, last)];
        e1 = csr[min(p + 1, last)];
        e2 = csr[min(p + 2, last)];
        e3 = csr[min(p + 3, last)];
        e4 = csr[min(p + 4, last)];
        e5 = csr[min(p + 5, last)];
        e6 = csr[min(p + 6, last)];
        e7 = csr[min(p + 7, last)];
        float w0 = (p + 0 < p1) ? __int_as_float(e0.y) : 0.f;
        float w1 = (p + 1 < p1) ? __int_as_float(e1.y) : 0.f;
        float w2 = (p + 2 < p1) ? __int_as_float(e2.y) : 0.f;
        float w3 = (p + 3 < p1) ? __int_as_float(e3.y) : 0.f;
        float w4 = (p + 4 < p1) ? __int_as_float(e4.y) : 0.f;
        float w5 = (p + 5 < p1) ? __int_as_float(e5.y) : 0.f;
        float w6 = (p + 6 < p1) ? __int_as_float(e6.y) : 0.f;
        float w7 = (p + 7 < p1) ? __int_as_float(e7.y) : 0.f;
        a0 += m[e0.x * HID + j] * w0;
        a1 += m[e1.x * HID + j] * w1;
        a2 += m[e2.x * HID + j] * w2;
        a3 += m[e3.x * HID + j] * w3;
        a4 += m[e4.x * HID + j] * w4;
        a5 += m[e5.x * HID + j] * w5;
        a6 += m[e6.x * HID + j] * w6;
        a7 += m[e7.x * HID + j] * w7;
    }
    float acc = ((a0 + a1) + (a2 + a3)) + ((a4 + a5) + (a6 + a7));
    float v = acc + bias[j];
    float s = v;
#pragma unroll
    for (int off = 32; off; off >>= 1) s += __shfl_xor(s, off, 64);
    float mu = s * (1.f / 64.f);
    float d = v - mu;
    float vv = d * d;
#pragma unroll
    for (int off = 32; off; off >>= 1) vv += __shfl_xor(vv, off, 64);
    float var = vv * (1.f / 64.f);
    float y = d * rsqrtf(var + EPS) * g[j] + b[j];
    hout[row * HID + j] = fmaxf(y, 0.f);
}

// ---------------- pooling: sliced segmented reduction -----------------------
#define NSLICE 16
__global__ __launch_bounds__(256) void k_pool2(const float* __restrict__ h,
                                               const int* __restrict__ start,
                                               float* __restrict__ sums,
                                               unsigned* __restrict__ maxs) {
    int gph = blockIdx.x >> 4;          // / NSLICE
    int sl  = blockIdx.x & (NSLICE - 1);
    int s = start[gph], e1 = start[gph + 1];
    int len = e1 - s;
    int chunk = (len + NSLICE - 1) / NSLICE;
    int r0 = s + sl * chunk;
    int r1 = min(r0 + chunk, e1);
    int j = threadIdx.x & 63, wv = threadIdx.x >> 6;
    float sm = 0.f, mx = 0.f;           // post-ReLU values >= 0
    for (int r = r0 + wv; r < r1; r += 4) {
        float v = h[r * HID + j];
        sm += v;
        mx = fmaxf(mx, v);
    }
    atomicAdd(&sums[gph * HID + j], sm);
    atomicMax(&maxs[gph * HID + j], __float_as_uint(mx));
}

// ---------------- final MLP: relu([mean,max] @ W1 + b1) @ W2 + b2 -----------
__global__ __launch_bounds__(64) void k_mlp(const float* __restrict__ sums,
                                            const unsigned* __restrict__ maxs,
                                            const int* __restrict__ start,
                                            const float* __restrict__ W1,
                                            const float* __restrict__ b1,
                                            const float* __restrict__ W2,
                                            const float* __restrict__ b2,
                                            float* __restrict__ out) {
    int gph = blockIdx.x;
    int j = threadIdx.x;          // 64 threads
    __shared__ float gv[2 * HID];
    int cnt = start[gph + 1] - start[gph];
    float inv = 1.f / fmaxf((float)cnt, 1.f);
    gv[j] = sums[gph * HID + j] * inv;
    float mx = __uint_as_float(maxs[gph * HID + j]);
    gv[HID + j] = (cnt > 0) ? mx : 0.f;
    __syncthreads();
    float acc = b1[j];
#pragma unroll
    for (int k = 0; k < 2 * HID; ++k) acc += gv[k] * W1[k * HID + j];
    acc = fmaxf(acc, 0.f);
    float p = acc * W2[j];
#pragma unroll
    for (int off = 32; off; off >>= 1) p += __shfl_xor(p, off, 64);
    if (j == 0) out[gph] = p + b2[0];
}

extern "C" void kernel_launch(void* const* d_in, const int* in_sizes, int n_in,
                              void* d_out, int out_size, void* d_ws, size_t ws_size,
                              hipStream_t stream) {
    const int*   x     = (const int*)d_in[0];
    const int*   ei    = (const int*)d_in[1];
    const float* ew    = (const float*)d_in[2];
    const int*   batch = (const int*)d_in[3];
    const float* emb   = (const float*)d_in[4];
    const float* convW = (const float*)d_in[5];
    const float* convB = (const float*)d_in[6];
    const float* lnG   = (const float*)d_in[7];
    const float* lnB   = (const float*)d_in[8];
    const float* W1    = (const float*)d_in[9];
    const float* b1    = (const float*)d_in[10];
    const float* W2    = (const float*)d_in[11];
    const float* b2    = (const float*)d_in[12];
    float* out = (float*)d_out;

    // ---- workspace layout ----
    float* hA     = (float*)d_ws;                       // 12.8 MB
    float* m      = hA + (size_t)N_NODES * HID;         // 12.8 MB
    int*   rowptr = (int*)(m + (size_t)N_NODES * HID);  // 50001
    int*   deg    = rowptr + (N_NODES + 1);             // 50000 (becomes cursor)
    int2*  csr    = (int2*)(deg + N_NODES);             // 1.25M * 8B = 10 MB
    float* sums   = (float*)(csr + N_EDGES);            // 64*64
    unsigned* maxs = (unsigned*)(sums + N_GRAPHS * HID);
    int*   start  = (int*)(maxs + N_GRAPHS * HID);      // 65
    int*   bsum   = start + (N_GRAPHS + 1);             // 196

    const int* src = ei;
    const int* dst = ei + N_EDGES;

    // ---- CSR build (per call; ws is re-poisoned) ----
    hipMemsetAsync(deg, 0, N_NODES * sizeof(int), stream);
    k_hist<<<(N_EDGES + 255) / 256, 256, 0, stream>>>(dst, deg);
    k_scan_a<<<SCAN_NB, SCAN_B, 0, stream>>>(deg, bsum);
    k_scan_b<<<1, 256, 0, stream>>>(bsum, rowptr, batch, start, sums, maxs);
    k_scan_c<<<SCAN_NB, SCAN_B, 0, stream>>>(deg, bsum, rowptr);
    k_fill<<<(N_EDGES + 255) / 256, 256, 0, stream>>>(src, dst, ew, deg, csr);

    for (int L = 0; L < N_LAYERS; ++L) {
        // layer 0 gathers emb rows through x (fused embedding)
        k_linear<<<N_NODES / 4, 256, 0, stream>>>(
            (L == 0) ? emb : hA, (L == 0) ? x : nullptr,
            convW + L * HID * HID, m);
        k_agg_ln<<<(N_NODES + 3) / 4, 256, 0, stream>>>(
            m, rowptr, csr, convB + L * HID, lnG + L * HID, lnB + L * HID, hA);
    }

    k_pool2<<<N_GRAPHS * NSLICE, 256, 0, stream>>>(hA, start, sums, maxs);
    k_mlp<<<N_GRAPHS, 64, 0, stream>>>(sums, maxs, start, W1, b1, W2, b2, out);
}